// Round 1
// baseline (4773.902 us; speedup 1.0000x reference)
//
#include <hip/hip_runtime.h>

#define CCH 256      // channels
#define BM  64       // rows per block in GEMM
#define BK  32       // K-step
#define KTOT 512     // mean(256) ++ x_dst(256)
#define LDSA_ST 40   // padded LDS stride (bf16 elems)
#define LDSB_ST 40

using f32x4  = __attribute__((ext_vector_type(4))) float;
using bf16x8 = __attribute__((ext_vector_type(8))) short;
using s16x4  = __attribute__((ext_vector_type(4))) short;

__device__ __forceinline__ unsigned short f2bf(float f) {
    union { float f; unsigned u; } v; v.f = f;
    unsigned r = v.u + 0x7FFFu + ((v.u >> 16) & 1u);   // RNE
    return (unsigned short)(r >> 16);
}

// ---------------- scatter: agg[dst] += x_src[src]; cnt[dst] += 1 ----------------
__global__ __launch_bounds__(256)
void scatter_kernel(const float* __restrict__ xsrc, const int* __restrict__ ei,
                    int E, float* __restrict__ agg, float* __restrict__ cnt) {
    int gtid = blockIdx.x * blockDim.x + threadIdx.x;
    int wid  = gtid >> 6;
    int lane = threadIdx.x & 63;
    int nw   = (gridDim.x * blockDim.x) >> 6;
    for (int e = wid; e < E; e += nw) {
        int src = ei[e];
        int dst = ei[E + e];
        float4 v = *((const float4*)(xsrc + (size_t)src * CCH) + lane);
        float* arow = agg + (size_t)dst * CCH + lane * 4;
        unsafeAtomicAdd(arow + 0, v.x);
        unsafeAtomicAdd(arow + 1, v.y);
        unsafeAtomicAdd(arow + 2, v.z);
        unsafeAtomicAdd(arow + 3, v.w);
        if (lane == 0) unsafeAtomicAdd(cnt + dst, 1.0f);
    }
}

// ------------- fused: out = LNReLU( (agg/cnt)@Wl^T + bl + x_dst@Wr^T ) -------------
__global__ __launch_bounds__(256)
void sage_gemm_ln(const float* __restrict__ agg, const float* __restrict__ cnt,
                  const float* __restrict__ xdst, const float* __restrict__ Wl,
                  const float* __restrict__ bl,   const float* __restrict__ Wr,
                  const float* __restrict__ gamma, const float* __restrict__ beta,
                  float* __restrict__ xout, int Nrows)
{
    __shared__ __align__(16) unsigned short As[BM][LDSA_ST];
    __shared__ __align__(16) unsigned short Bs[CCH][LDSB_ST];
    __shared__ float rinv_s[BM];

    const int tid  = threadIdx.x;
    const int lane = tid & 63;
    const int w    = tid >> 6;
    const long brow = (long)blockIdx.x * BM;

    if (tid < BM) {
        long r = brow + tid;
        float c = (r < Nrows) ? cnt[r] : 1.0f;
        rinv_s[tid] = 1.0f / fmaxf(c, 1.0f);
    }

    f32x4 acc[16];
#pragma unroll
    for (int f = 0; f < 16; ++f) acc[f] = (f32x4){0.f, 0.f, 0.f, 0.f};

    const int arow = tid >> 2;          // 0..63
    const int ak0  = (tid & 3) * 8;     // 0,8,16,24
    const int bk0  = (tid & 7) * 4;     // 0..28
    const int bcb  = tid >> 3;          // 0..31

    __syncthreads();  // rinv ready

    for (int kb = 0; kb < KTOT; kb += BK) {
        // ---- stage A (64 rows x 32 k, bf16) ----
        {
            long grow = brow + arow;
            float v[8];
            if (grow < Nrows) {
                if (kb < CCH) {
                    const float* p = agg + grow * CCH + kb + ak0;
                    float s = rinv_s[arow];
                    float4 u0 = *(const float4*)(p);
                    float4 u1 = *(const float4*)(p + 4);
                    v[0]=u0.x*s; v[1]=u0.y*s; v[2]=u0.z*s; v[3]=u0.w*s;
                    v[4]=u1.x*s; v[5]=u1.y*s; v[6]=u1.z*s; v[7]=u1.w*s;
                } else {
                    const float* p = xdst + grow * CCH + (kb - CCH) + ak0;
                    float4 u0 = *(const float4*)(p);
                    float4 u1 = *(const float4*)(p + 4);
                    v[0]=u0.x; v[1]=u0.y; v[2]=u0.z; v[3]=u0.w;
                    v[4]=u1.x; v[5]=u1.y; v[6]=u1.z; v[7]=u1.w;
                }
            } else {
#pragma unroll
                for (int i = 0; i < 8; ++i) v[i] = 0.f;
            }
            bf16x8 pk;
#pragma unroll
            for (int i = 0; i < 8; ++i) pk[i] = (short)f2bf(v[i]);
            *(bf16x8*)&As[arow][ak0] = pk;
        }
        // ---- stage B: Bs[col][k] = W[col][k]  (col-major-in-K fragments) ----
        {
            const float* W = (kb < CCH) ? Wl : Wr;
            int kk = kb & (CCH - 1);
#pragma unroll
            for (int jj = 0; jj < 8; ++jj) {
                int col = jj * 32 + bcb;
                float4 u = *(const float4*)(W + (size_t)col * CCH + kk + bk0);
                s16x4 pk;
                pk[0]=(short)f2bf(u.x); pk[1]=(short)f2bf(u.y);
                pk[2]=(short)f2bf(u.z); pk[3]=(short)f2bf(u.w);
                *(s16x4*)&Bs[col][bk0] = pk;
            }
        }
        __syncthreads();
        // ---- MFMA: wave w owns rows w*16..w*16+15, all 256 cols ----
        {
            const int koff = (lane >> 4) * 8;
            const int rA = w * 16 + (lane & 15);
            bf16x8 a = *(const bf16x8*)&As[rA][koff];
#pragma unroll
            for (int f = 0; f < 16; ++f) {
                bf16x8 b = *(const bf16x8*)&Bs[f * 16 + (lane & 15)][koff];
                acc[f] = __builtin_amdgcn_mfma_f32_16x16x32_bf16(a, b, acc[f], 0, 0, 0);
            }
        }
        __syncthreads();
    }

    // ---- epilogue: +bias, LayerNorm (per-row over 256 cols), ReLU, store ----
    const int cl = lane & 15;
    const int g4 = lane >> 4;
    float s1[4] = {0,0,0,0}, s2[4] = {0,0,0,0};
#pragma unroll
    for (int f = 0; f < 16; ++f) {
        float bv = bl[f * 16 + cl];
#pragma unroll
        for (int j = 0; j < 4; ++j) {
            float val = acc[f][j] + bv;
            acc[f][j] = val;
            s1[j] += val;
            s2[j] += val * val;
        }
    }
#pragma unroll
    for (int m = 1; m < 16; m <<= 1) {
#pragma unroll
        for (int j = 0; j < 4; ++j) {
            s1[j] += __shfl_xor(s1[j], m);
            s2[j] += __shfl_xor(s2[j], m);
        }
    }
    float mu[4], rs[4];
#pragma unroll
    for (int j = 0; j < 4; ++j) {
        mu[j] = s1[j] * (1.0f / CCH);
        float var = s2[j] * (1.0f / CCH) - mu[j] * mu[j];
        rs[j] = rsqrtf(var + 1e-5f);
    }
    const long rbase = brow + w * 16 + g4 * 4;
#pragma unroll
    for (int f = 0; f < 16; ++f) {
        float gm = gamma[f * 16 + cl];
        float bt = beta[f * 16 + cl];
#pragma unroll
        for (int j = 0; j < 4; ++j) {
            long r = rbase + j;
            if (r < Nrows) {
                float v = (acc[f][j] - mu[j]) * rs[j] * gm + bt;
                xout[r * CCH + f * 16 + cl] = fmaxf(v, 0.f);
            }
        }
    }
}

extern "C" void kernel_launch(void* const* d_in, const int* in_sizes, int n_in,
                              void* d_out, int out_size, void* d_ws, size_t ws_size,
                              hipStream_t stream) {
    const float* x_user = (const float*)d_in[0];
    const float* x_item = (const float*)d_in[1];
    const int*   ei_u2i = (const int*)d_in[2];
    const int*   ei_i2u = (const int*)d_in[3];
    const float* Wl_u2i = (const float*)d_in[4];
    const float* bl_u2i = (const float*)d_in[5];
    const float* Wr_u2i = (const float*)d_in[6];
    const float* Wl_i2u = (const float*)d_in[7];
    const float* bl_i2u = (const float*)d_in[8];
    const float* Wr_i2u = (const float*)d_in[9];
    const float* g_user = (const float*)d_in[10];
    const float* b_user = (const float*)d_in[11];
    const float* g_item = (const float*)d_in[12];
    const float* b_item = (const float*)d_in[13];

    const int N = in_sizes[0] / CCH;
    const int E = in_sizes[2] / 2;
    const size_t NC = (size_t)N * CCH;

    float* agg_i = (float*)d_ws;
    float* agg_u = agg_i + NC;
    float* cnt_i = agg_u + NC;
    float* cnt_u = cnt_i + N;

    float* out_user = (float*)d_out;
    float* out_item = out_user + NC;

    const int sc_blocks = 1024;
    const int gm_blocks = (N + BM - 1) / BM;

    for (int l = 0; l < 2; ++l) {
        const float* xu = (l == 0) ? x_user : out_user;
        const float* xi = (l == 0) ? x_item : out_item;
        hipMemsetAsync(agg_i, 0, NC * sizeof(float), stream);
        hipMemsetAsync(agg_u, 0, NC * sizeof(float), stream);
        hipMemsetAsync(cnt_i, 0, N * sizeof(float), stream);
        hipMemsetAsync(cnt_u, 0, N * sizeof(float), stream);
        scatter_kernel<<<sc_blocks, 256, 0, stream>>>(xu, ei_u2i, E, agg_i, cnt_i);
        scatter_kernel<<<sc_blocks, 256, 0, stream>>>(xi, ei_i2u, E, agg_u, cnt_u);
        // new_item = sage(x_user -> x_item), then LN(g_item,b_item)+ReLU
        sage_gemm_ln<<<gm_blocks, 256, 0, stream>>>(agg_i, cnt_i, xi,
            Wl_u2i + (size_t)l * CCH * CCH, bl_u2i + l * CCH,
            Wr_u2i + (size_t)l * CCH * CCH,
            g_item + l * CCH, b_item + l * CCH, out_item, N);
        // new_user = sage(x_item -> x_user), then LN(g_user,b_user)+ReLU
        sage_gemm_ln<<<gm_blocks, 256, 0, stream>>>(agg_u, cnt_u, xu,
            Wl_i2u + (size_t)l * CCH * CCH, bl_i2u + l * CCH,
            Wr_i2u + (size_t)l * CCH * CCH,
            g_user + l * CCH, b_user + l * CCH, out_user, N);
    }
}

// Round 2
// 1230.531 us; speedup vs baseline: 3.8795x; 3.8795x over previous
//
#include <hip/hip_runtime.h>

#define CCH 256      // channels
#define BM  64       // rows per block in GEMM
#define BK  32       // K-step
#define KTOT 512     // mean(256) ++ x_dst(256)
#define LDSA_ST 40   // padded LDS stride (bf16 elems)
#define LDSB_ST 40

using f32x4  = __attribute__((ext_vector_type(4))) float;
using bf16x8 = __attribute__((ext_vector_type(8))) short;
using s16x4  = __attribute__((ext_vector_type(4))) short;

__device__ __forceinline__ unsigned short f2bf(float f) {
    union { float f; unsigned u; } v; v.f = f;
    unsigned r = v.u + 0x7FFFu + ((v.u >> 16) & 1u);   // RNE
    return (unsigned short)(r >> 16);
}

// ---------------- CSR build ----------------
__global__ __launch_bounds__(256)
void hist_kernel(const int* __restrict__ ei, int E, int* __restrict__ cnt) {
    int e = blockIdx.x * blockDim.x + threadIdx.x;
    if (e < E) atomicAdd(&cnt[ei[E + e]], 1);
}

// single-block exclusive scan: rowstart[i] = sum(cnt[0..i)), rowstart[N] = E
__global__ __launch_bounds__(1024)
void scan_kernel(const int* __restrict__ cnt, int N, int E, int* __restrict__ rowstart) {
    __shared__ int s[1024];
    const int tid = threadIdx.x;
    const int seg = (N + 1023) >> 10;
    const int lo = tid * seg;
    const int hi = min(lo + seg, N);
    int sum = 0;
    for (int i = lo; i < hi; ++i) sum += cnt[i];
    s[tid] = sum;
    __syncthreads();
    for (int o = 1; o < 1024; o <<= 1) {
        int t = 0;
        if (tid >= o) t = s[tid - o];
        __syncthreads();
        if (tid >= o) s[tid] += t;
        __syncthreads();
    }
    int run = s[tid] - sum;   // exclusive prefix of this segment
    for (int i = lo; i < hi; ++i) { rowstart[i] = run; run += cnt[i]; }
    if (tid == 0) rowstart[N] = E;
}

__global__ __launch_bounds__(256)
void fill_kernel(const int* __restrict__ ei, int E, const int* __restrict__ rowstart,
                 int* __restrict__ cursor, int* __restrict__ elist) {
    int e = blockIdx.x * blockDim.x + threadIdx.x;
    if (e < E) {
        int dst = ei[E + e];
        int p = atomicAdd(&cursor[dst], 1);
        elist[rowstart[dst] + p] = ei[e];   // src node id
    }
}

// ------------- gather + mean (bf16 out): one wave per dst node -------------
__global__ __launch_bounds__(256)
void gather_mean(const float* __restrict__ xsrc, const int* __restrict__ rowstart,
                 const int* __restrict__ elist, unsigned short* __restrict__ mean, int N) {
    int wid  = (blockIdx.x * blockDim.x + threadIdx.x) >> 6;
    int lane = threadIdx.x & 63;
    if (wid >= N) return;
    int lo = rowstart[wid], hi = rowstart[wid + 1];
    f32x4 acc = (f32x4){0.f, 0.f, 0.f, 0.f};
    for (int i = lo; i < hi; ++i) {
        int s = elist[i];
        float4 v = *((const float4*)(xsrc + (size_t)s * CCH) + lane);
        acc[0] += v.x; acc[1] += v.y; acc[2] += v.z; acc[3] += v.w;
    }
    float r = (hi > lo) ? 1.0f / (float)(hi - lo) : 0.0f;
    s16x4 pk;
#pragma unroll
    for (int j = 0; j < 4; ++j) pk[j] = (short)f2bf(acc[j] * r);
    *(s16x4*)(mean + (size_t)wid * CCH + lane * 4) = pk;
}

// ------------- fused: out = LNReLU( mean@Wl^T + bl + x_dst@Wr^T ) -------------
__global__ __launch_bounds__(256)
void sage_gemm_ln(const unsigned short* __restrict__ mean,
                  const float* __restrict__ xdst, const float* __restrict__ Wl,
                  const float* __restrict__ bl,   const float* __restrict__ Wr,
                  const float* __restrict__ gamma, const float* __restrict__ beta,
                  float* __restrict__ xout, int Nrows)
{
    __shared__ __align__(16) unsigned short As[BM][LDSA_ST];
    __shared__ __align__(16) unsigned short Bs[CCH][LDSB_ST];

    const int tid  = threadIdx.x;
    const int lane = tid & 63;
    const int w    = tid >> 6;
    const long brow = (long)blockIdx.x * BM;

    f32x4 acc[16];
#pragma unroll
    for (int f = 0; f < 16; ++f) acc[f] = (f32x4){0.f, 0.f, 0.f, 0.f};

    const int arow = tid >> 2;          // 0..63
    const int ak0  = (tid & 3) * 8;     // 0,8,16,24
    const int bk0  = (tid & 7) * 4;     // 0..28
    const int bcb  = tid >> 3;          // 0..31

    for (int kb = 0; kb < KTOT; kb += BK) {
        // ---- stage A (64 rows x 32 k, bf16) ----
        {
            long grow = brow + arow;
            bf16x8 pk;
            if (grow < Nrows) {
                if (kb < CCH) {
                    pk = *(const bf16x8*)(mean + grow * CCH + kb + ak0);
                } else {
                    const float* p = xdst + grow * CCH + (kb - CCH) + ak0;
                    float4 u0 = *(const float4*)(p);
                    float4 u1 = *(const float4*)(p + 4);
                    pk[0]=(short)f2bf(u0.x); pk[1]=(short)f2bf(u0.y);
                    pk[2]=(short)f2bf(u0.z); pk[3]=(short)f2bf(u0.w);
                    pk[4]=(short)f2bf(u1.x); pk[5]=(short)f2bf(u1.y);
                    pk[6]=(short)f2bf(u1.z); pk[7]=(short)f2bf(u1.w);
                }
            } else {
#pragma unroll
                for (int i = 0; i < 8; ++i) pk[i] = 0;
            }
            *(bf16x8*)&As[arow][ak0] = pk;
        }
        // ---- stage B: Bs[col][k] = W[col][k] ----
        {
            const float* W = (kb < CCH) ? Wl : Wr;
            int kk = kb & (CCH - 1);
#pragma unroll
            for (int jj = 0; jj < 8; ++jj) {
                int col = jj * 32 + bcb;
                float4 u = *(const float4*)(W + (size_t)col * CCH + kk + bk0);
                s16x4 pk;
                pk[0]=(short)f2bf(u.x); pk[1]=(short)f2bf(u.y);
                pk[2]=(short)f2bf(u.z); pk[3]=(short)f2bf(u.w);
                *(s16x4*)&Bs[col][bk0] = pk;
            }
        }
        __syncthreads();
        // ---- MFMA: wave w owns rows w*16..w*16+15, all 256 cols ----
        {
            const int koff = (lane >> 4) * 8;
            const int rA = w * 16 + (lane & 15);
            bf16x8 a = *(const bf16x8*)&As[rA][koff];
#pragma unroll
            for (int f = 0; f < 16; ++f) {
                bf16x8 b = *(const bf16x8*)&Bs[f * 16 + (lane & 15)][koff];
                acc[f] = __builtin_amdgcn_mfma_f32_16x16x32_bf16(a, b, acc[f], 0, 0, 0);
            }
        }
        __syncthreads();
    }

    // ---- epilogue: +bias, LayerNorm (per-row over 256 cols), ReLU, store ----
    const int cl = lane & 15;
    const int g4 = lane >> 4;
    float s1[4] = {0,0,0,0}, s2[4] = {0,0,0,0};
#pragma unroll
    for (int f = 0; f < 16; ++f) {
        float bv = bl[f * 16 + cl];
#pragma unroll
        for (int j = 0; j < 4; ++j) {
            float val = acc[f][j] + bv;
            acc[f][j] = val;
            s1[j] += val;
            s2[j] += val * val;
        }
    }
#pragma unroll
    for (int m = 1; m < 16; m <<= 1) {
#pragma unroll
        for (int j = 0; j < 4; ++j) {
            s1[j] += __shfl_xor(s1[j], m);
            s2[j] += __shfl_xor(s2[j], m);
        }
    }
    float mu[4], rs[4];
#pragma unroll
    for (int j = 0; j < 4; ++j) {
        mu[j] = s1[j] * (1.0f / CCH);
        float var = s2[j] * (1.0f / CCH) - mu[j] * mu[j];
        rs[j] = rsqrtf(var + 1e-5f);
    }
    const long rbase = brow + w * 16 + g4 * 4;
#pragma unroll
    for (int f = 0; f < 16; ++f) {
        float gm = gamma[f * 16 + cl];
        float bt = beta[f * 16 + cl];
#pragma unroll
        for (int j = 0; j < 4; ++j) {
            long r = rbase + j;
            if (r < Nrows) {
                float v = (acc[f][j] - mu[j]) * rs[j] * gm + bt;
                xout[r * CCH + f * 16 + cl] = fmaxf(v, 0.f);
            }
        }
    }
}

extern "C" void kernel_launch(void* const* d_in, const int* in_sizes, int n_in,
                              void* d_out, int out_size, void* d_ws, size_t ws_size,
                              hipStream_t stream) {
    const float* x_user = (const float*)d_in[0];
    const float* x_item = (const float*)d_in[1];
    const int*   ei_u2i = (const int*)d_in[2];
    const int*   ei_i2u = (const int*)d_in[3];
    const float* Wl_u2i = (const float*)d_in[4];
    const float* bl_u2i = (const float*)d_in[5];
    const float* Wr_u2i = (const float*)d_in[6];
    const float* Wl_i2u = (const float*)d_in[7];
    const float* bl_i2u = (const float*)d_in[8];
    const float* Wr_i2u = (const float*)d_in[9];
    const float* g_user = (const float*)d_in[10];
    const float* b_user = (const float*)d_in[11];
    const float* g_item = (const float*)d_in[12];
    const float* b_item = (const float*)d_in[13];

    const int N = in_sizes[0] / CCH;
    const int E = in_sizes[2] / 2;
    const size_t NC = (size_t)N * CCH;

    // workspace layout
    char* p = (char*)d_ws;
    unsigned short* mean_i = (unsigned short*)p; p += NC * sizeof(unsigned short);
    unsigned short* mean_u = (unsigned short*)p; p += NC * sizeof(unsigned short);
    int* cnt_i  = (int*)p; p += (size_t)N * sizeof(int);
    int* cnt_u  = (int*)p; p += (size_t)N * sizeof(int);
    int* rs_i   = (int*)p; p += (size_t)(N + 1) * sizeof(int);
    int* rs_u   = (int*)p; p += (size_t)(N + 1) * sizeof(int);
    int* el_i   = (int*)p; p += (size_t)E * sizeof(int);
    int* el_u   = (int*)p; p += (size_t)E * sizeof(int);

    float* out_user = (float*)d_out;
    float* out_item = out_user + NC;

    const int eb = (E + 255) / 256;
    const int gm_blocks = (N + BM - 1) / BM;
    const int gw_blocks = (N + 3) / 4;          // 4 waves (nodes) per 256-thr block

    // ---- CSR build (edges are layer-invariant: build once per call) ----
    hipMemsetAsync(cnt_i, 0, (size_t)N * sizeof(int), stream);
    hipMemsetAsync(cnt_u, 0, (size_t)N * sizeof(int), stream);
    hist_kernel<<<eb, 256, 0, stream>>>(ei_u2i, E, cnt_i);
    hist_kernel<<<eb, 256, 0, stream>>>(ei_i2u, E, cnt_u);
    scan_kernel<<<1, 1024, 0, stream>>>(cnt_i, N, E, rs_i);
    scan_kernel<<<1, 1024, 0, stream>>>(cnt_u, N, E, rs_u);
    hipMemsetAsync(cnt_i, 0, (size_t)N * sizeof(int), stream);
    hipMemsetAsync(cnt_u, 0, (size_t)N * sizeof(int), stream);
    fill_kernel<<<eb, 256, 0, stream>>>(ei_u2i, E, rs_i, cnt_i, el_i);
    fill_kernel<<<eb, 256, 0, stream>>>(ei_i2u, E, rs_u, cnt_u, el_u);

    for (int l = 0; l < 2; ++l) {
        const float* xu = (l == 0) ? x_user : out_user;
        const float* xi = (l == 0) ? x_item : out_item;
        gather_mean<<<gw_blocks, 256, 0, stream>>>(xu, rs_i, el_i, mean_i, N);
        gather_mean<<<gw_blocks, 256, 0, stream>>>(xi, rs_u, el_u, mean_u, N);
        // new_item = sage(x_user -> x_item), then LN(g_item,b_item)+ReLU
        sage_gemm_ln<<<gm_blocks, 256, 0, stream>>>(mean_i, xi,
            Wl_u2i + (size_t)l * CCH * CCH, bl_u2i + l * CCH,
            Wr_u2i + (size_t)l * CCH * CCH,
            g_item + l * CCH, b_item + l * CCH, out_item, N);
        // new_user = sage(x_item -> x_user), then LN(g_user,b_user)+ReLU
        sage_gemm_ln<<<gm_blocks, 256, 0, stream>>>(mean_u, xu,
            Wl_i2u + (size_t)l * CCH * CCH, bl_i2u + l * CCH,
            Wr_i2u + (size_t)l * CCH * CCH,
            g_user + l * CCH, b_user + l * CCH, out_user, N);
    }
}

// Round 4
// 849.844 us; speedup vs baseline: 5.6174x; 1.4479x over previous
//
#include <hip/hip_runtime.h>

#define CCH 256      // channels
#define BM  64       // rows per block in GEMM
#define BK  32       // K-step
#define KTOT 512     // mean(256) ++ x_dst(256)
#define LDSA_ST 40   // padded LDS stride (bf16 elems)
#define LDSB_ST 40
#define SCB 2048     // scan elems per block (256 thr x 8)

using f32x4  = __attribute__((ext_vector_type(4))) float;
using bf16x8 = __attribute__((ext_vector_type(8))) short;
using s16x4  = __attribute__((ext_vector_type(4))) short;

__device__ __forceinline__ unsigned short f2bf(float f) {
    union { float f; unsigned u; } v; v.f = f;
    unsigned r = v.u + 0x7FFFu + ((v.u >> 16) & 1u);   // RNE
    return (unsigned short)(r >> 16);
}
__device__ __forceinline__ float bf2f(short h) {
    union { unsigned u; float f; } v;
    v.u = ((unsigned)(unsigned short)h) << 16;
    return v.f;
}

// ---------------- fp32 -> bf16 convert ----------------
__global__ __launch_bounds__(256)
void cvt_bf16(const float* __restrict__ x, unsigned short* __restrict__ y, long n) {
    long i = ((long)blockIdx.x * 256 + threadIdx.x) * 8;
    if (i >= n) return;
    float4 a = *(const float4*)(x + i);
    float4 b = *(const float4*)(x + i + 4);
    bf16x8 pk;
    pk[0]=(short)f2bf(a.x); pk[1]=(short)f2bf(a.y); pk[2]=(short)f2bf(a.z); pk[3]=(short)f2bf(a.w);
    pk[4]=(short)f2bf(b.x); pk[5]=(short)f2bf(b.y); pk[6]=(short)f2bf(b.z); pk[7]=(short)f2bf(b.w);
    *(bf16x8*)(y + i) = pk;
}

// ---------------- CSR build ----------------
__global__ __launch_bounds__(256)
void hist_kernel(const int* __restrict__ ei, int E, int* __restrict__ cnt) {
    int e = blockIdx.x * blockDim.x + threadIdx.x;
    if (e < E) atomicAdd(&cnt[ei[E + e]], 1);
}

// pass 1: per-block sums of 2048 counters
__global__ __launch_bounds__(256)
void scan_part(const int* __restrict__ cnt, int N, int* __restrict__ bsum) {
    __shared__ int sw[4];
    int t = threadIdx.x;
    int base = blockIdx.x * SCB + t * 8;
    int s = 0;
#pragma unroll
    for (int j = 0; j < 8; ++j) { int idx = base + j; s += (idx < N) ? cnt[idx] : 0; }
    for (int m = 1; m < 64; m <<= 1) s += __shfl_xor(s, m);
    if ((t & 63) == 0) sw[t >> 6] = s;
    __syncthreads();
    if (t == 0) bsum[blockIdx.x] = sw[0] + sw[1] + sw[2] + sw[3];
}

// pass 2: exclusive-scan the (<=256) block sums; grid.x=2 picks array
__global__ __launch_bounds__(256)
void scan_bsum(int* __restrict__ ba, int* __restrict__ bb, int nb) {
    int* b = blockIdx.x ? bb : ba;
    __shared__ int s[256];
    int t = threadIdx.x;
    int v = (t < nb) ? b[t] : 0;
    s[t] = v;
    __syncthreads();
    for (int o = 1; o < 256; o <<= 1) {
        int u = 0;
        if (t >= o) u = s[t - o];
        __syncthreads();
        if (t >= o) s[t] += u;
        __syncthreads();
    }
    if (t < nb) b[t] = s[t] - v;   // exclusive
}

// pass 3: write rowstart, zero cursor (cursor may alias cnt)
__global__ __launch_bounds__(256)
void scan_apply(const int* __restrict__ cnt, const int* __restrict__ bsum,
                int N, int E, int* __restrict__ rowstart, int* __restrict__ cursor) {
    __shared__ int sw[4];
    int t = threadIdx.x;
    int base = blockIdx.x * SCB + t * 8;
    int v[8]; int s = 0;
#pragma unroll
    for (int j = 0; j < 8; ++j) { int idx = base + j; v[j] = (idx < N) ? cnt[idx] : 0; s += v[j]; }
    int own = s;
    for (int m = 1; m < 64; m <<= 1) {          // inclusive wave scan
        int u = __shfl_up(s, m);
        if ((t & 63) >= m) s += u;
    }
    if ((t & 63) == 63) sw[t >> 6] = s;
    __syncthreads();
    int w = t >> 6, woff = 0;
    if (w > 0) woff += sw[0];
    if (w > 1) woff += sw[1];
    if (w > 2) woff += sw[2];
    int excl = bsum[blockIdx.x] + woff + s - own;
#pragma unroll
    for (int j = 0; j < 8; ++j) {
        int idx = base + j;
        if (idx < N) { rowstart[idx] = excl; excl += v[j]; cursor[idx] = 0; }
    }
    if (blockIdx.x == 0 && t == 0) rowstart[N] = E;
}

__global__ __launch_bounds__(256)
void fill_kernel(const int* __restrict__ ei, int E, const int* __restrict__ rowstart,
                 int* __restrict__ cursor, int* __restrict__ elist) {
    int e = blockIdx.x * blockDim.x + threadIdx.x;
    if (e < E) {
        int dst = ei[E + e];
        int p = atomicAdd(&cursor[dst], 1);
        elist[rowstart[dst] + p] = ei[e];   // src node id
    }
}

// ------------- gather + mean (bf16 in/out): one wave per dst node -------------
__global__ __launch_bounds__(256)
void gather_mean(const unsigned short* __restrict__ xsrc, const int* __restrict__ rowstart,
                 const int* __restrict__ elist, unsigned short* __restrict__ mean, int N) {
    int wid  = (blockIdx.x * blockDim.x + threadIdx.x) >> 6;
    int lane = threadIdx.x & 63;
    if (wid >= N) return;
    int lo = rowstart[wid], hi = rowstart[wid + 1];
    float a0 = 0.f, a1 = 0.f, a2 = 0.f, a3 = 0.f;
    for (int i = lo; i < hi; ++i) {
        int s = elist[i];
        s16x4 v = *((const s16x4*)(xsrc + (size_t)s * CCH) + lane);
        a0 += bf2f(v[0]); a1 += bf2f(v[1]); a2 += bf2f(v[2]); a3 += bf2f(v[3]);
    }
    float r = (hi > lo) ? 1.0f / (float)(hi - lo) : 0.0f;
    s16x4 pk;
    pk[0] = (short)f2bf(a0 * r); pk[1] = (short)f2bf(a1 * r);
    pk[2] = (short)f2bf(a2 * r); pk[3] = (short)f2bf(a3 * r);
    *((s16x4*)(mean + (size_t)wid * CCH) + lane) = pk;
}

// ------- fused: h = LNReLU( mean@Wl^T + bl + xdst@Wr^T ); write fp32 and/or bf16 -------
__global__ __launch_bounds__(256)
void sage_gemm_ln(const unsigned short* __restrict__ mean,
                  const unsigned short* __restrict__ xdst, const float* __restrict__ Wl,
                  const float* __restrict__ bl,   const float* __restrict__ Wr,
                  const float* __restrict__ gamma, const float* __restrict__ beta,
                  float* __restrict__ outf, unsigned short* __restrict__ outb, int Nrows)
{
    __shared__ __align__(16) unsigned short As[BM][LDSA_ST];
    __shared__ __align__(16) unsigned short Bs[CCH][LDSB_ST];

    const int tid  = threadIdx.x;
    const int lane = tid & 63;
    const int w    = tid >> 6;
    const long brow = (long)blockIdx.x * BM;

    f32x4 acc[16];
#pragma unroll
    for (int f = 0; f < 16; ++f) acc[f] = (f32x4){0.f, 0.f, 0.f, 0.f};

    const int arow = tid >> 2;          // 0..63
    const int ak0  = (tid & 3) * 8;     // 0,8,16,24
    const int bk0  = (tid & 7) * 4;     // 0..28
    const int bcb  = tid >> 3;          // 0..31

    for (int kb = 0; kb < KTOT; kb += BK) {
        // ---- stage A (64 rows x 32 k, bf16 direct) ----
        {
            long grow = brow + arow;
            bf16x8 pk;
            if (grow < Nrows) {
                const unsigned short* src = (kb < CCH) ? mean : xdst;
                pk = *(const bf16x8*)(src + grow * CCH + (kb & (CCH - 1)) + ak0);
            } else {
#pragma unroll
                for (int i = 0; i < 8; ++i) pk[i] = 0;
            }
            *(bf16x8*)&As[arow][ak0] = pk;
        }
        // ---- stage B: Bs[col][k] = W[col][k] ----
        {
            const float* W = (kb < CCH) ? Wl : Wr;
            int kk = kb & (CCH - 1);
#pragma unroll
            for (int jj = 0; jj < 8; ++jj) {
                int col = jj * 32 + bcb;
                float4 u = *(const float4*)(W + (size_t)col * CCH + kk + bk0);
                s16x4 pk;
                pk[0]=(short)f2bf(u.x); pk[1]=(short)f2bf(u.y);
                pk[2]=(short)f2bf(u.z); pk[3]=(short)f2bf(u.w);
                *(s16x4*)&Bs[col][bk0] = pk;
            }
        }
        __syncthreads();
        // ---- MFMA: wave w owns rows w*16..w*16+15, all 256 cols ----
        {
            const int koff = (lane >> 4) * 8;
            const int rA = w * 16 + (lane & 15);
            bf16x8 a = *(const bf16x8*)&As[rA][koff];
#pragma unroll
            for (int f = 0; f < 16; ++f) {
                bf16x8 b = *(const bf16x8*)&Bs[f * 16 + (lane & 15)][koff];
                acc[f] = __builtin_amdgcn_mfma_f32_16x16x32_bf16(a, b, acc[f], 0, 0, 0);
            }
        }
        __syncthreads();
    }

    // ---- epilogue: +bias, LayerNorm (per-row over 256 cols), ReLU, store ----
    const int cl = lane & 15;
    const int g4 = lane >> 4;
    float s1[4] = {0,0,0,0}, s2[4] = {0,0,0,0};
#pragma unroll
    for (int f = 0; f < 16; ++f) {
        float bv = bl[f * 16 + cl];
#pragma unroll
        for (int j = 0; j < 4; ++j) {
            float val = acc[f][j] + bv;
            acc[f][j] = val;
            s1[j] += val;
            s2[j] += val * val;
        }
    }
#pragma unroll
    for (int m = 1; m < 16; m <<= 1) {
#pragma unroll
        for (int j = 0; j < 4; ++j) {
            s1[j] += __shfl_xor(s1[j], m);
            s2[j] += __shfl_xor(s2[j], m);
        }
    }
    float mu[4], rs[4];
#pragma unroll
    for (int j = 0; j < 4; ++j) {
        mu[j] = s1[j] * (1.0f / CCH);
        float var = s2[j] * (1.0f / CCH) - mu[j] * mu[j];
        rs[j] = rsqrtf(var + 1e-5f);
    }
    const long rbase = brow + w * 16 + g4 * 4;
#pragma unroll
    for (int f = 0; f < 16; ++f) {
        float gm = gamma[f * 16 + cl];
        float bt = beta[f * 16 + cl];
#pragma unroll
        for (int j = 0; j < 4; ++j) {
            long r = rbase + j;
            if (r < Nrows) {
                float v = (acc[f][j] - mu[j]) * rs[j] * gm + bt;
                v = fmaxf(v, 0.f);
                if (outf) outf[r * CCH + f * 16 + cl] = v;
                if (outb) outb[r * CCH + f * 16 + cl] = f2bf(v);
            }
        }
    }
}

extern "C" void kernel_launch(void* const* d_in, const int* in_sizes, int n_in,
                              void* d_out, int out_size, void* d_ws, size_t ws_size,
                              hipStream_t stream) {
    const float* x_user = (const float*)d_in[0];
    const float* x_item = (const float*)d_in[1];
    const int*   ei_u2i = (const int*)d_in[2];
    const int*   ei_i2u = (const int*)d_in[3];
    const float* Wl_u2i = (const float*)d_in[4];
    const float* bl_u2i = (const float*)d_in[5];
    const float* Wr_u2i = (const float*)d_in[6];
    const float* Wl_i2u = (const float*)d_in[7];
    const float* bl_i2u = (const float*)d_in[8];
    const float* Wr_i2u = (const float*)d_in[9];
    const float* g_user = (const float*)d_in[10];
    const float* b_user = (const float*)d_in[11];
    const float* g_item = (const float*)d_in[12];
    const float* b_item = (const float*)d_in[13];

    const int N = in_sizes[0] / CCH;
    const int E = in_sizes[2] / 2;
    const size_t NC = (size_t)N * CCH;
    const int nb = (N + SCB - 1) / SCB;

    // workspace layout (~210 MB)
    char* p = (char*)d_ws;
    unsigned short* xb_u   = (unsigned short*)p; p += NC * sizeof(unsigned short); // layer1 in / layer1 out (user)
    unsigned short* xb_i   = (unsigned short*)p; p += NC * sizeof(unsigned short); // layer1 in / layer1 out (item)
    unsigned short* mean_i = (unsigned short*)p; p += NC * sizeof(unsigned short);
    unsigned short* mean_u = (unsigned short*)p; p += NC * sizeof(unsigned short);
    int* cnt_i  = (int*)p; p += (size_t)N * sizeof(int);   // doubles as fill cursor
    int* cnt_u  = (int*)p; p += (size_t)N * sizeof(int);
    int* rs_i   = (int*)p; p += (size_t)(N + 1) * sizeof(int);
    int* rs_u   = (int*)p; p += (size_t)(N + 1) * sizeof(int);
    int* el_i   = (int*)p; p += (size_t)E * sizeof(int);
    int* el_u   = (int*)p; p += (size_t)E * sizeof(int);
    int* bs_i   = (int*)p; p += 256 * sizeof(int);
    int* bs_u   = (int*)p; p += 256 * sizeof(int);

    float* out_user = (float*)d_out;
    float* out_item = out_user + NC;

    const int eb = (E + 255) / 256;
    const int cb = (int)((NC / 8 + 255) / 256);
    const int gm_blocks = (N + BM - 1) / BM;
    const int gw_blocks = (N + 3) / 4;          // 4 waves (nodes) per 256-thr block

    // ---- CSR build ----
    hipMemsetAsync(cnt_i, 0, (size_t)N * sizeof(int), stream);
    hipMemsetAsync(cnt_u, 0, (size_t)N * sizeof(int), stream);
    hist_kernel<<<eb, 256, 0, stream>>>(ei_u2i, E, cnt_i);
    hist_kernel<<<eb, 256, 0, stream>>>(ei_i2u, E, cnt_u);
    scan_part<<<nb, 256, 0, stream>>>(cnt_i, N, bs_i);
    scan_part<<<nb, 256, 0, stream>>>(cnt_u, N, bs_u);
    scan_bsum<<<2, 256, 0, stream>>>(bs_i, bs_u, nb);
    scan_apply<<<nb, 256, 0, stream>>>(cnt_i, bs_i, N, E, rs_i, cnt_i);
    scan_apply<<<nb, 256, 0, stream>>>(cnt_u, bs_u, N, E, rs_u, cnt_u);
    fill_kernel<<<eb, 256, 0, stream>>>(ei_u2i, E, rs_i, cnt_i, el_i);
    fill_kernel<<<eb, 256, 0, stream>>>(ei_i2u, E, rs_u, cnt_u, el_u);

    // ---- bf16 copies of inputs ----
    cvt_bf16<<<cb, 256, 0, stream>>>(x_user, xb_u, (long)NC);
    cvt_bf16<<<cb, 256, 0, stream>>>(x_item, xb_i, (long)NC);

    // ---- layer 1 (bf16 activations in-place over xb_*) ----
    gather_mean<<<gw_blocks, 256, 0, stream>>>(xb_u, rs_i, el_i, mean_i, N);
    gather_mean<<<gw_blocks, 256, 0, stream>>>(xb_i, rs_u, el_u, mean_u, N);
    sage_gemm_ln<<<gm_blocks, 256, 0, stream>>>(mean_i, xb_i,
        Wl_u2i, bl_u2i, Wr_u2i, g_item, b_item, nullptr, xb_i, N);
    sage_gemm_ln<<<gm_blocks, 256, 0, stream>>>(mean_u, xb_u,
        Wl_i2u, bl_i2u, Wr_i2u, g_user, b_user, nullptr, xb_u, N);

    // ---- layer 2 (fp32 out to d_out) ----
    gather_mean<<<gw_blocks, 256, 0, stream>>>(xb_u, rs_i, el_i, mean_i, N);
    gather_mean<<<gw_blocks, 256, 0, stream>>>(xb_i, rs_u, el_u, mean_u, N);
    sage_gemm_ln<<<gm_blocks, 256, 0, stream>>>(mean_i, xb_i,
        Wl_u2i + (size_t)CCH * CCH, bl_u2i + CCH, Wr_u2i + (size_t)CCH * CCH,
        g_item + CCH, b_item + CCH, out_item, nullptr, N);
    sage_gemm_ln<<<gm_blocks, 256, 0, stream>>>(mean_u, xb_u,
        Wl_i2u + (size_t)CCH * CCH, bl_i2u + CCH, Wr_i2u + (size_t)CCH * CCH,
        g_user + CCH, b_user + CCH, out_user, nullptr, N);
}